// Round 1
// baseline (1882.158 us; speedup 1.0000x reference)
//
#include <hip/hip_runtime.h>
#include <hip/hip_bf16.h>

#define NND 100000
#define NED 3200000
#define F 256
#define NCLS 64

typedef short s16x8 __attribute__((ext_vector_type(8)));
typedef float f32x4 __attribute__((ext_vector_type(4)));

static __device__ __forceinline__ unsigned short f2bf(float f) {
    unsigned int u = __float_as_uint(f);
    u = u + 0x7fffu + ((u >> 16) & 1u);   // round-to-nearest-even
    return (unsigned short)(u >> 16);
}

// ---------------- degree / norm ----------------
__global__ __launch_bounds__(256) void k_deg(const int* __restrict__ dst, int* __restrict__ deg) {
    int i = blockIdx.x * 256 + threadIdx.x;
    if (i < NED) atomicAdd(&deg[dst[i]], 1);
}

__global__ __launch_bounds__(256) void k_norm(const int* __restrict__ deg, float* __restrict__ norm) {
    int i = blockIdx.x * 256 + threadIdx.x;
    if (i < NND) {
        float d = (float)deg[i];
        norm[i] = rsqrtf(d < 1.0f ? 1.0f : d);
    }
}

// ---------------- CSR build: scan + fill ----------------
__global__ __launch_bounds__(256) void k_scan1(const int* __restrict__ deg, int* __restrict__ start, int* __restrict__ bsum) {
    __shared__ int sh[256];
    int i = blockIdx.x * 256 + threadIdx.x;
    int v = (i < NND) ? deg[i] : 0;
    sh[threadIdx.x] = v;
    __syncthreads();
    for (int off = 1; off < 256; off <<= 1) {
        int t = (threadIdx.x >= off) ? sh[threadIdx.x - off] : 0;
        __syncthreads();
        sh[threadIdx.x] += t;
        __syncthreads();
    }
    if (i < NND) start[i] = sh[threadIdx.x] - v;  // exclusive within block
    if (threadIdx.x == 255) bsum[blockIdx.x] = sh[255];
}

__global__ __launch_bounds__(512) void k_scan2(int* __restrict__ bsum, int nb) {
    __shared__ int sh[512];
    int tid = threadIdx.x;
    int v = (tid < nb) ? bsum[tid] : 0;
    sh[tid] = v;
    __syncthreads();
    for (int off = 1; off < 512; off <<= 1) {
        int t = (tid >= off) ? sh[tid - off] : 0;
        __syncthreads();
        sh[tid] += t;
        __syncthreads();
    }
    if (tid < nb) bsum[tid] = sh[tid] - v;  // exclusive
}

__global__ __launch_bounds__(256) void k_scan3(int* __restrict__ start, const int* __restrict__ bsum) {
    int i = blockIdx.x * 256 + threadIdx.x;
    if (i < NND) start[i] += bsum[blockIdx.x];
}

__global__ __launch_bounds__(256) void k_fill(const int* __restrict__ src, const int* __restrict__ dst,
                                              const int* __restrict__ start, int* __restrict__ cursor,
                                              int* __restrict__ col) {
    int i = blockIdx.x * 256 + threadIdx.x;
    if (i < NED) {
        int d = dst[i];
        int p = start[d] + atomicAdd(&cursor[d], 1);
        col[p] = src[i];
    }
}

// ---------------- LayerNorm (one wave per node) ----------------
__global__ __launch_bounds__(256) void k_ln(const float* __restrict__ x, const float* __restrict__ gamma,
                                            const float* __restrict__ beta, float* __restrict__ y) {
    int node = blockIdx.x * 4 + (threadIdx.x >> 6);
    int lane = threadIdx.x & 63;
    if (node >= NND) return;
    float4 v = ((const float4*)x)[node * 64 + lane];
    float s = v.x + v.y + v.z + v.w;
    float s2 = v.x * v.x + v.y * v.y + v.z * v.z + v.w * v.w;
    for (int m = 1; m < 64; m <<= 1) {
        s += __shfl_xor(s, m, 64);
        s2 += __shfl_xor(s2, m, 64);
    }
    float mu = s * (1.0f / 256.0f);
    float var = s2 * (1.0f / 256.0f) - mu * mu;
    float rs = rsqrtf(var + 1e-5f);
    float4 g = ((const float4*)gamma)[lane];
    float4 b = ((const float4*)beta)[lane];
    float4 o;
    o.x = (v.x - mu) * rs * g.x + b.x;
    o.y = (v.y - mu) * rs * g.y + b.y;
    o.z = (v.z - mu) * rs * g.z + b.z;
    o.w = (v.w - mu) * rs * g.w + b.w;
    ((float4*)y)[node * 64 + lane] = o;
}

// ---------------- one propagation hop (one wave per dst node) ----------------
__global__ __launch_bounds__(256) void k_hop(const float* __restrict__ x, float* __restrict__ y,
                                             const int* __restrict__ start, const int* __restrict__ deg,
                                             const int* __restrict__ col, const float* __restrict__ norm) {
    int node = __builtin_amdgcn_readfirstlane(blockIdx.x * 4 + (threadIdx.x >> 6));
    int lane = threadIdx.x & 63;
    if (node >= NND) return;
    int s0 = start[node];
    int cnt = deg[node];
    float ax = 0.f, ay = 0.f, az = 0.f, aw = 0.f;
    for (int e = 0; e < cnt; e++) {
        int s = col[s0 + e];
        float w = norm[s];
        float4 v = ((const float4*)x)[s * 64 + lane];
        ax += w * v.x;
        ay += w * v.y;
        az += w * v.z;
        aw += w * v.w;
    }
    float wd = norm[node];
    float4 o;
    o.x = ax * wd; o.y = ay * wd; o.z = az * wd; o.w = aw * wd;
    ((float4*)y)[node * 64 + lane] = o;
}

// ---------------- fp32 -> bf16 cast ----------------
__global__ __launch_bounds__(256) void k_cast4(const float4* __restrict__ x, ushort4* __restrict__ y, int n4) {
    int i = blockIdx.x * 256 + threadIdx.x;
    if (i < n4) {
        float4 v = x[i];
        ushort4 o;
        o.x = f2bf(v.x); o.y = f2bf(v.y); o.z = f2bf(v.z); o.w = f2bf(v.w);
        y[i] = o;
    }
}

// ---------------- GEMM1: [M,256] x [256,256]^T + bias, ReLU -> bf16 ----------------
__global__ __launch_bounds__(256) void k_gemm1(const unsigned short* __restrict__ A,
                                               const unsigned short* __restrict__ W,
                                               const float* __restrict__ bias,
                                               unsigned short* __restrict__ out) {
    int wave = threadIdx.x >> 6, lane = threadIdx.x & 63;
    int l15 = lane & 15, lhi = lane >> 4;
    int row0 = blockIdx.x * 16;
    const unsigned short* arow = A + (size_t)(row0 + l15) * F + lhi * 8;
    int ncol0 = wave * 64;
    f32x4 acc[4];
    for (int t = 0; t < 4; t++) acc[t] = (f32x4){0.f, 0.f, 0.f, 0.f};
#pragma unroll
    for (int kt = 0; kt < 8; kt++) {
        s16x8 a = *(const s16x8*)(arow + kt * 32);
#pragma unroll
        for (int t = 0; t < 4; t++) {
            int n = ncol0 + t * 16 + l15;
            s16x8 b = *(const s16x8*)(W + (size_t)n * F + lhi * 8 + kt * 32);
            acc[t] = __builtin_amdgcn_mfma_f32_16x16x32_bf16(a, b, acc[t], 0, 0, 0);
        }
    }
#pragma unroll
    for (int t = 0; t < 4; t++) {
        int colb = ncol0 + t * 16 + l15;
        float bv = bias[colb];
#pragma unroll
        for (int r = 0; r < 4; r++) {
            int row = row0 + lhi * 4 + r;
            float v = acc[t][r] + bv;
            v = v > 0.f ? v : 0.f;
            out[(size_t)row * F + colb] = f2bf(v);
        }
    }
}

// ---------------- GEMM2: [M,256] x [256,64]^T + bias -> fp32 ----------------
__global__ __launch_bounds__(256) void k_gemm2(const unsigned short* __restrict__ A,
                                               const unsigned short* __restrict__ W,
                                               const float* __restrict__ bias,
                                               float* __restrict__ out) {
    int wave = threadIdx.x >> 6, lane = threadIdx.x & 63;
    int gw = blockIdx.x * 4 + wave;
    if (gw >= NND / 16) return;
    int l15 = lane & 15, lhi = lane >> 4;
    int row0 = gw * 16;
    const unsigned short* arow = A + (size_t)(row0 + l15) * F + lhi * 8;
    f32x4 acc[4];
    for (int t = 0; t < 4; t++) acc[t] = (f32x4){0.f, 0.f, 0.f, 0.f};
#pragma unroll
    for (int kt = 0; kt < 8; kt++) {
        s16x8 a = *(const s16x8*)(arow + kt * 32);
#pragma unroll
        for (int t = 0; t < 4; t++) {
            int n = t * 16 + l15;
            s16x8 b = *(const s16x8*)(W + (size_t)n * F + lhi * 8 + kt * 32);
            acc[t] = __builtin_amdgcn_mfma_f32_16x16x32_bf16(a, b, acc[t], 0, 0, 0);
        }
    }
#pragma unroll
    for (int t = 0; t < 4; t++) {
        int colb = t * 16 + l15;
        float bv = bias[colb];
#pragma unroll
        for (int r = 0; r < 4; r++) {
            int row = row0 + lhi * 4 + r;
            out[(size_t)row * NCLS + colb] = acc[t][r] + bv;
        }
    }
}

extern "C" void kernel_launch(void* const* d_in, const int* in_sizes, int n_in,
                              void* d_out, int out_size, void* d_ws, size_t ws_size,
                              hipStream_t stream) {
    const float* features = (const float*)d_in[0];
    const int* edge_src = (const int*)d_in[1];
    const int* edge_dst = (const int*)d_in[2];
    const float* ln_gamma = (const float*)d_in[3];
    const float* ln_beta = (const float*)d_in[4];
    const float* W_conv = (const float*)d_in[5];
    const float* b_conv = (const float*)d_in[6];
    const float* W_fc = (const float*)d_in[7];
    const float* b_fc = (const float*)d_in[8];
    float* out = (float*)d_out;

    char* w = (char*)d_ws;
    const size_t HBYTES = (size_t)NND * F * 4;        // 102,400,000
    float* hA = (float*)(w + 0);
    float* hB = (float*)(w + HBYTES);
    int* col = (int*)(w + 2 * HBYTES);                // 204,800,000
    int* deg = (int*)(w + 217600000);
    int* start = (int*)(w + 218000000);
    int* cursor = (int*)(w + 218400000);
    float* norm = (float*)(w + 218800000);
    int* bsum = (int*)(w + 219200000);
    unsigned short* Wc16 = (unsigned short*)(w + 219202048);
    unsigned short* Wf16 = (unsigned short*)(w + 219333120);
    // bf16 h3 and mid alias hA (free after hop3)
    unsigned short* h3_16 = (unsigned short*)(w + 0);
    unsigned short* mid16 = (unsigned short*)(w + HBYTES / 2);

    hipMemsetAsync(deg, 0, NND * sizeof(int), stream);
    hipMemsetAsync(cursor, 0, NND * sizeof(int), stream);

    const int EB = (NED + 255) / 256;   // 12500
    const int NB = (NND + 255) / 256;   // 391

    k_deg<<<EB, 256, 0, stream>>>(edge_dst, deg);
    k_norm<<<NB, 256, 0, stream>>>(deg, norm);
    k_scan1<<<NB, 256, 0, stream>>>(deg, start, bsum);
    k_scan2<<<1, 512, 0, stream>>>(bsum, NB);
    k_scan3<<<NB, 256, 0, stream>>>(start, bsum);
    k_fill<<<EB, 256, 0, stream>>>(edge_src, edge_dst, start, cursor, col);

    k_ln<<<NND / 4, 256, 0, stream>>>(features, ln_gamma, ln_beta, hA);

    k_hop<<<NND / 4, 256, 0, stream>>>(hA, hB, start, deg, col, norm);
    k_hop<<<NND / 4, 256, 0, stream>>>(hB, hA, start, deg, col, norm);
    k_hop<<<NND / 4, 256, 0, stream>>>(hA, hB, start, deg, col, norm);

    k_cast4<<<(NND * F / 4 + 255) / 256, 256, 0, stream>>>((const float4*)hB, (ushort4*)h3_16, NND * F / 4);
    k_cast4<<<(F * F / 4 + 255) / 256, 256, 0, stream>>>((const float4*)W_conv, (ushort4*)Wc16, F * F / 4);
    k_cast4<<<(NCLS * F / 4 + 255) / 256, 256, 0, stream>>>((const float4*)W_fc, (ushort4*)Wf16, NCLS * F / 4);

    k_gemm1<<<NND / 16, 256, 0, stream>>>(h3_16, Wc16, b_conv, mid16);
    k_gemm2<<<(NND / 16 + 3) / 4, 256, 0, stream>>>(mid16, Wf16, b_fc, out);
}

// Round 2
// 1221.310 us; speedup vs baseline: 1.5411x; 1.5411x over previous
//
#include <hip/hip_runtime.h>
#include <hip/hip_bf16.h>

#define NND 100000
#define NED 3200000
#define F 256
#define NCLS 64

typedef _Float16 f16x8 __attribute__((ext_vector_type(8)));
typedef _Float16 f16x4 __attribute__((ext_vector_type(4)));
typedef float f32x4 __attribute__((ext_vector_type(4)));

// ---------------- degree / norm ----------------
__global__ __launch_bounds__(256) void k_deg(const int* __restrict__ dst, int* __restrict__ deg) {
    int i = blockIdx.x * 256 + threadIdx.x;
    if (i < NED) atomicAdd(&deg[dst[i]], 1);
}

__global__ __launch_bounds__(256) void k_norm(const int* __restrict__ deg, float* __restrict__ norm) {
    int i = blockIdx.x * 256 + threadIdx.x;
    if (i < NND) {
        float d = (float)deg[i];
        norm[i] = rsqrtf(d < 1.0f ? 1.0f : d);
    }
}

// ---------------- CSR build: scan + fill ----------------
__global__ __launch_bounds__(256) void k_scan1(const int* __restrict__ deg, int* __restrict__ start, int* __restrict__ bsum) {
    __shared__ int sh[256];
    int i = blockIdx.x * 256 + threadIdx.x;
    int v = (i < NND) ? deg[i] : 0;
    sh[threadIdx.x] = v;
    __syncthreads();
    for (int off = 1; off < 256; off <<= 1) {
        int t = (threadIdx.x >= off) ? sh[threadIdx.x - off] : 0;
        __syncthreads();
        sh[threadIdx.x] += t;
        __syncthreads();
    }
    if (i < NND) start[i] = sh[threadIdx.x] - v;  // exclusive within block
    if (threadIdx.x == 255) bsum[blockIdx.x] = sh[255];
}

__global__ __launch_bounds__(512) void k_scan2(int* __restrict__ bsum, int nb) {
    __shared__ int sh[512];
    int tid = threadIdx.x;
    int v = (tid < nb) ? bsum[tid] : 0;
    sh[tid] = v;
    __syncthreads();
    for (int off = 1; off < 512; off <<= 1) {
        int t = (tid >= off) ? sh[tid - off] : 0;
        __syncthreads();
        sh[tid] += t;
        __syncthreads();
    }
    if (tid < nb) bsum[tid] = sh[tid] - v;  // exclusive
}

__global__ __launch_bounds__(256) void k_scan3(int* __restrict__ start, const int* __restrict__ bsum) {
    int i = blockIdx.x * 256 + threadIdx.x;
    if (i < NND) start[i] += bsum[blockIdx.x];
}

__global__ __launch_bounds__(256) void k_fill(const int* __restrict__ src, const int* __restrict__ dst,
                                              const int* __restrict__ start, int* __restrict__ cursor,
                                              int* __restrict__ col) {
    int i = blockIdx.x * 256 + threadIdx.x;
    if (i < NED) {
        int d = dst[i];
        int p = start[d] + atomicAdd(&cursor[d], 1);
        col[p] = src[i];
    }
}

// ---------------- LayerNorm (one wave per node) -> fp16 ----------------
__global__ __launch_bounds__(256) void k_ln(const float* __restrict__ x, const float* __restrict__ gamma,
                                            const float* __restrict__ beta, _Float16* __restrict__ y) {
    int node = blockIdx.x * 4 + (threadIdx.x >> 6);
    int lane = threadIdx.x & 63;
    if (node >= NND) return;
    float4 v = ((const float4*)x)[node * 64 + lane];
    float s = v.x + v.y + v.z + v.w;
    float s2 = v.x * v.x + v.y * v.y + v.z * v.z + v.w * v.w;
    for (int m = 1; m < 64; m <<= 1) {
        s += __shfl_xor(s, m, 64);
        s2 += __shfl_xor(s2, m, 64);
    }
    float mu = s * (1.0f / 256.0f);
    float var = s2 * (1.0f / 256.0f) - mu * mu;
    float rs = rsqrtf(var + 1e-5f);
    float4 g = ((const float4*)gamma)[lane];
    float4 b = ((const float4*)beta)[lane];
    f16x4 o;
    o[0] = (_Float16)((v.x - mu) * rs * g.x + b.x);
    o[1] = (_Float16)((v.y - mu) * rs * g.y + b.y);
    o[2] = (_Float16)((v.z - mu) * rs * g.z + b.z);
    o[3] = (_Float16)((v.w - mu) * rs * g.w + b.w);
    *(f16x4*)(y + (size_t)node * F + lane * 4) = o;
}

// ---------------- one propagation hop (one wave per dst node, 2 edges/iter) ----------------
__global__ __launch_bounds__(256) void k_hop(const _Float16* __restrict__ x, _Float16* __restrict__ y,
                                             const int* __restrict__ start, const int* __restrict__ deg,
                                             const int* __restrict__ col, const float* __restrict__ norm) {
    int node = __builtin_amdgcn_readfirstlane(blockIdx.x * 4 + (threadIdx.x >> 6));
    if (node >= NND) return;
    int lane = threadIdx.x & 63;
    int hf = lane >> 5;       // which edge of the pair
    int l = lane & 31;        // 32 lanes x 8 halfs = 256 feats
    int s0 = start[node];
    int cnt = deg[node];
    float acc[8] = {0.f, 0.f, 0.f, 0.f, 0.f, 0.f, 0.f, 0.f};
    int npair = (cnt + 1) >> 1;
    for (int i = 0; i < npair; i++) {
        int e = 2 * i + hf;
        int s = 0;
        float w = 0.f;
        if (e < cnt) {
            s = col[s0 + e];
            w = norm[s];
        }
        f16x8 v = *(const f16x8*)(x + (size_t)s * F + l * 8);
#pragma unroll
        for (int j = 0; j < 8; j++) acc[j] += w * (float)v[j];
    }
#pragma unroll
    for (int j = 0; j < 8; j++) acc[j] += __shfl_xor(acc[j], 32, 64);
    if (hf == 0) {
        float wd = norm[node];
        f16x8 o;
#pragma unroll
        for (int j = 0; j < 8; j++) o[j] = (_Float16)(acc[j] * wd);
        *(f16x8*)(y + (size_t)node * F + l * 8) = o;
    }
}

// ---------------- fp32 -> fp16 cast (weights) ----------------
__global__ __launch_bounds__(256) void k_cast(const float4* __restrict__ x, f16x4* __restrict__ y, int n4) {
    int i = blockIdx.x * 256 + threadIdx.x;
    if (i < n4) {
        float4 v = x[i];
        f16x4 o;
        o[0] = (_Float16)v.x; o[1] = (_Float16)v.y; o[2] = (_Float16)v.z; o[3] = (_Float16)v.w;
        y[i] = o;
    }
}

// ---------------- GEMM1: [M,256] x [256,256]^T + bias, ReLU -> fp16 ----------------
__global__ __launch_bounds__(256) void k_gemm1(const _Float16* __restrict__ A,
                                               const _Float16* __restrict__ W,
                                               const float* __restrict__ bias,
                                               _Float16* __restrict__ out) {
    int wave = threadIdx.x >> 6, lane = threadIdx.x & 63;
    int l15 = lane & 15, lhi = lane >> 4;
    int row0 = blockIdx.x * 16;
    const _Float16* arow = A + (size_t)(row0 + l15) * F + lhi * 8;
    int ncol0 = wave * 64;
    f32x4 acc[4];
    for (int t = 0; t < 4; t++) acc[t] = (f32x4){0.f, 0.f, 0.f, 0.f};
#pragma unroll
    for (int kt = 0; kt < 8; kt++) {
        f16x8 a = *(const f16x8*)(arow + kt * 32);
#pragma unroll
        for (int t = 0; t < 4; t++) {
            int n = ncol0 + t * 16 + l15;
            f16x8 b = *(const f16x8*)(W + (size_t)n * F + lhi * 8 + kt * 32);
            acc[t] = __builtin_amdgcn_mfma_f32_16x16x32_f16(a, b, acc[t], 0, 0, 0);
        }
    }
#pragma unroll
    for (int t = 0; t < 4; t++) {
        int colb = ncol0 + t * 16 + l15;
        float bv = bias[colb];
#pragma unroll
        for (int r = 0; r < 4; r++) {
            int row = row0 + lhi * 4 + r;
            float v = acc[t][r] + bv;
            v = v > 0.f ? v : 0.f;
            out[(size_t)row * F + colb] = (_Float16)v;
        }
    }
}

// ---------------- GEMM2: [M,256] x [256,64]^T + bias -> fp32 ----------------
__global__ __launch_bounds__(256) void k_gemm2(const _Float16* __restrict__ A,
                                               const _Float16* __restrict__ W,
                                               const float* __restrict__ bias,
                                               float* __restrict__ out) {
    int wave = threadIdx.x >> 6, lane = threadIdx.x & 63;
    int gw = blockIdx.x * 4 + wave;
    if (gw >= NND / 16) return;
    int l15 = lane & 15, lhi = lane >> 4;
    int row0 = gw * 16;
    const _Float16* arow = A + (size_t)(row0 + l15) * F + lhi * 8;
    f32x4 acc[4];
    for (int t = 0; t < 4; t++) acc[t] = (f32x4){0.f, 0.f, 0.f, 0.f};
#pragma unroll
    for (int kt = 0; kt < 8; kt++) {
        f16x8 a = *(const f16x8*)(arow + kt * 32);
#pragma unroll
        for (int t = 0; t < 4; t++) {
            int n = t * 16 + l15;
            f16x8 b = *(const f16x8*)(W + (size_t)n * F + lhi * 8 + kt * 32);
            acc[t] = __builtin_amdgcn_mfma_f32_16x16x32_f16(a, b, acc[t], 0, 0, 0);
        }
    }
#pragma unroll
    for (int t = 0; t < 4; t++) {
        int colb = t * 16 + l15;
        float bv = bias[colb];
#pragma unroll
        for (int r = 0; r < 4; r++) {
            int row = row0 + lhi * 4 + r;
            out[(size_t)row * NCLS + colb] = acc[t][r] + bv;
        }
    }
}

extern "C" void kernel_launch(void* const* d_in, const int* in_sizes, int n_in,
                              void* d_out, int out_size, void* d_ws, size_t ws_size,
                              hipStream_t stream) {
    const float* features = (const float*)d_in[0];
    const int* edge_src = (const int*)d_in[1];
    const int* edge_dst = (const int*)d_in[2];
    const float* ln_gamma = (const float*)d_in[3];
    const float* ln_beta = (const float*)d_in[4];
    const float* W_conv = (const float*)d_in[5];
    const float* b_conv = (const float*)d_in[6];
    const float* W_fc = (const float*)d_in[7];
    const float* b_fc = (const float*)d_in[8];
    float* out = (float*)d_out;

    char* w = (char*)d_ws;
    const size_t HB2 = (size_t)NND * F * 2;            // 51,200,000 (fp16 h)
    _Float16* hA = (_Float16*)(w + 0);
    _Float16* hB = (_Float16*)(w + HB2);
    int* col = (int*)(w + 2 * HB2);                    // 102,400,000
    int* deg = (int*)(w + 115200000);
    int* start = (int*)(w + 115600000);
    int* cursor = (int*)(w + 116000000);
    float* norm = (float*)(w + 116400000);
    int* bsum = (int*)(w + 116800000);
    _Float16* Wc16 = (_Float16*)(w + 116802048);
    _Float16* Wf16 = (_Float16*)(w + 116933120);
    _Float16* mid = hA;                                // free after hop3 (hop3 writes hB)

    hipMemsetAsync(deg, 0, NND * sizeof(int), stream);
    hipMemsetAsync(cursor, 0, NND * sizeof(int), stream);

    const int EB = (NED + 255) / 256;   // 12500
    const int NB = (NND + 255) / 256;   // 391

    k_deg<<<EB, 256, 0, stream>>>(edge_dst, deg);
    k_norm<<<NB, 256, 0, stream>>>(deg, norm);
    k_scan1<<<NB, 256, 0, stream>>>(deg, start, bsum);
    k_scan2<<<1, 512, 0, stream>>>(bsum, NB);
    k_scan3<<<NB, 256, 0, stream>>>(start, bsum);
    k_fill<<<EB, 256, 0, stream>>>(edge_src, edge_dst, start, cursor, col);

    k_ln<<<NND / 4, 256, 0, stream>>>(features, ln_gamma, ln_beta, hA);

    k_hop<<<NND / 4, 256, 0, stream>>>(hA, hB, start, deg, col, norm);
    k_hop<<<NND / 4, 256, 0, stream>>>(hB, hA, start, deg, col, norm);
    k_hop<<<NND / 4, 256, 0, stream>>>(hA, hB, start, deg, col, norm);

    k_cast<<<(F * F / 4 + 255) / 256, 256, 0, stream>>>((const float4*)W_conv, (f16x4*)Wc16, F * F / 4);
    k_cast<<<(NCLS * F / 4 + 255) / 256, 256, 0, stream>>>((const float4*)W_fc, (f16x4*)Wf16, NCLS * F / 4);

    k_gemm1<<<NND / 16, 256, 0, stream>>>(hB, Wc16, b_conv, mid);
    k_gemm2<<<(NND / 16 + 3) / 4, 256, 0, stream>>>(mid, Wf16, b_fc, out);
}

// Round 3
// 1135.188 us; speedup vs baseline: 1.6580x; 1.0759x over previous
//
#include <hip/hip_runtime.h>
#include <hip/hip_bf16.h>

#define NND 100000
#define NED 3200000
#define F 256
#define NCLS 64

typedef _Float16 f16x8 __attribute__((ext_vector_type(8)));
typedef _Float16 f16x4 __attribute__((ext_vector_type(4)));
typedef float f32x4 __attribute__((ext_vector_type(4)));

// ---------------- degree ----------------
__global__ __launch_bounds__(256) void k_deg(const int* __restrict__ dst, int* __restrict__ deg) {
    int i = blockIdx.x * 256 + threadIdx.x;
    if (i < NED) atomicAdd(&deg[dst[i]], 1);
}

// ---------------- CSR build: scan + fill ----------------
__global__ __launch_bounds__(256) void k_scan1(const int* __restrict__ deg, int* __restrict__ start, int* __restrict__ bsum) {
    __shared__ int sh[256];
    int i = blockIdx.x * 256 + threadIdx.x;
    int v = (i < NND) ? deg[i] : 0;
    sh[threadIdx.x] = v;
    __syncthreads();
    for (int off = 1; off < 256; off <<= 1) {
        int t = (threadIdx.x >= off) ? sh[threadIdx.x - off] : 0;
        __syncthreads();
        sh[threadIdx.x] += t;
        __syncthreads();
    }
    if (i < NND) start[i] = sh[threadIdx.x] - v;  // exclusive within block
    if (threadIdx.x == 255) bsum[blockIdx.x] = sh[255];
}

__global__ __launch_bounds__(512) void k_scan2(int* __restrict__ bsum, int nb) {
    __shared__ int sh[512];
    int tid = threadIdx.x;
    int v = (tid < nb) ? bsum[tid] : 0;
    sh[tid] = v;
    __syncthreads();
    for (int off = 1; off < 512; off <<= 1) {
        int t = (tid >= off) ? sh[tid - off] : 0;
        __syncthreads();
        sh[tid] += t;
        __syncthreads();
    }
    if (tid < nb) bsum[tid] = sh[tid] - v;  // exclusive
}

// scan3 + norm fused
__global__ __launch_bounds__(256) void k_scan3(int* __restrict__ start, const int* __restrict__ bsum,
                                               const int* __restrict__ deg, float* __restrict__ norm) {
    int i = blockIdx.x * 256 + threadIdx.x;
    if (i < NND) {
        start[i] += bsum[blockIdx.x];
        float d = (float)deg[i];
        norm[i] = rsqrtf(d < 1.0f ? 1.0f : d);
    }
}

__global__ __launch_bounds__(256) void k_fill(const int* __restrict__ src, const int* __restrict__ dst,
                                              const int* __restrict__ start, int* __restrict__ cursor,
                                              int* __restrict__ col) {
    int i = blockIdx.x * 256 + threadIdx.x;
    if (i < NED) {
        int d = dst[i];
        int p = start[d] + atomicAdd(&cursor[d], 1);
        col[p] = src[i];
    }
}

// ---------------- LayerNorm (one wave per node) -> pre-scaled fp16 (norm * LN) ----------------
__global__ __launch_bounds__(256) void k_ln(const float* __restrict__ x, const float* __restrict__ gamma,
                                            const float* __restrict__ beta, const float* __restrict__ norm,
                                            _Float16* __restrict__ y) {
    int node = blockIdx.x * 4 + (threadIdx.x >> 6);
    int lane = threadIdx.x & 63;
    if (node >= NND) return;
    float4 v = ((const float4*)x)[node * 64 + lane];
    float s = v.x + v.y + v.z + v.w;
    float s2 = v.x * v.x + v.y * v.y + v.z * v.z + v.w * v.w;
    for (int m = 1; m < 64; m <<= 1) {
        s += __shfl_xor(s, m, 64);
        s2 += __shfl_xor(s2, m, 64);
    }
    float mu = s * (1.0f / 256.0f);
    float var = s2 * (1.0f / 256.0f) - mu * mu;
    float rs = rsqrtf(var + 1e-5f);
    float w = norm[node];
    float4 g = ((const float4*)gamma)[lane];
    float4 b = ((const float4*)beta)[lane];
    f16x4 o;
    o[0] = (_Float16)(w * ((v.x - mu) * rs * g.x + b.x));
    o[1] = (_Float16)(w * ((v.y - mu) * rs * g.y + b.y));
    o[2] = (_Float16)(w * ((v.z - mu) * rs * g.z + b.z));
    o[3] = (_Float16)(w * ((v.w - mu) * rs * g.w + b.w));
    *(f16x4*)(y + (size_t)node * F + lane * 4) = o;
}

// ---------------- one propagation hop ----------------
// x is pre-scaled by norm. LAST=0: write norm^2 * sum (pre-scaled for next hop).
// LAST=1: write norm * sum (final h3 for the GEMM).
template <int LAST>
__global__ __launch_bounds__(256) void k_hop(const _Float16* __restrict__ x, _Float16* __restrict__ y,
                                             const int* __restrict__ start, const int* __restrict__ deg,
                                             const int* __restrict__ col, const float* __restrict__ norm) {
    int node = __builtin_amdgcn_readfirstlane(blockIdx.x * 4 + (threadIdx.x >> 6));
    if (node >= NND) return;
    int lane = threadIdx.x & 63;
    int hf = lane >> 5;       // which edge of the pair
    int l = lane & 31;        // 32 lanes x 8 halfs = 256 feats
    int s0 = start[node];
    int cnt = deg[node];
    float acc[8] = {0.f, 0.f, 0.f, 0.f, 0.f, 0.f, 0.f, 0.f};
    for (int base = 0; base < cnt; base += 64) {
        int rem = cnt - base;
        int cv = (lane < rem) ? col[s0 + base + lane] : 0;
        int npair = rem > 64 ? 32 : (rem >> 1);
#pragma unroll 2
        for (int i = 0; i < npair; i++) {
            int s = __shfl(cv, 2 * i + hf, 64);
            f16x8 v = *(const f16x8*)(x + (size_t)s * F + l * 8);
#pragma unroll
            for (int j = 0; j < 8; j++) acc[j] += (float)v[j];
        }
        if ((rem & 1) && rem <= 64) {   // odd leftover edge in final chunk
            int s = __shfl(cv, rem - 1, 64);
            if (hf == 0) {
                f16x8 v = *(const f16x8*)(x + (size_t)s * F + l * 8);
#pragma unroll
                for (int j = 0; j < 8; j++) acc[j] += (float)v[j];
            }
        }
    }
#pragma unroll
    for (int j = 0; j < 8; j++) acc[j] += __shfl_xor(acc[j], 32, 64);
    if (hf == 0) {
        float wd = norm[node];
        float sc = LAST ? wd : wd * wd;
        f16x8 o;
#pragma unroll
        for (int j = 0; j < 8; j++) o[j] = (_Float16)(acc[j] * sc);
        *(f16x8*)(y + (size_t)node * F + l * 8) = o;
    }
}

// ---------------- fp32 -> fp16 cast (weights) ----------------
__global__ __launch_bounds__(256) void k_cast(const float4* __restrict__ x, f16x4* __restrict__ y, int n4) {
    int i = blockIdx.x * 256 + threadIdx.x;
    if (i < n4) {
        float4 v = x[i];
        f16x4 o;
        o[0] = (_Float16)v.x; o[1] = (_Float16)v.y; o[2] = (_Float16)v.z; o[3] = (_Float16)v.w;
        y[i] = o;
    }
}

// ---------------- fused GEMM: relu(h3 @ Wc^T + bc) @ Wf^T + bf ----------------
__global__ __launch_bounds__(256) void k_gemm(const _Float16* __restrict__ A,
                                              const _Float16* __restrict__ Wc, const float* __restrict__ bc,
                                              const _Float16* __restrict__ Wf, const float* __restrict__ bf,
                                              float* __restrict__ out) {
    __shared__ _Float16 mid[16][264];   // +8 pad kills bank conflicts
    int wave = threadIdx.x >> 6, lane = threadIdx.x & 63;
    int l15 = lane & 15, lhi = lane >> 4;
    int row0 = blockIdx.x * 16;
    const _Float16* arow = A + (size_t)(row0 + l15) * F + lhi * 8;
    int ncol0 = wave * 64;
    f32x4 acc[4];
    for (int t = 0; t < 4; t++) acc[t] = (f32x4){0.f, 0.f, 0.f, 0.f};
#pragma unroll
    for (int kt = 0; kt < 8; kt++) {
        f16x8 a = *(const f16x8*)(arow + kt * 32);
#pragma unroll
        for (int t = 0; t < 4; t++) {
            int n = ncol0 + t * 16 + l15;
            f16x8 b = *(const f16x8*)(Wc + (size_t)n * F + lhi * 8 + kt * 32);
            acc[t] = __builtin_amdgcn_mfma_f32_16x16x32_f16(a, b, acc[t], 0, 0, 0);
        }
    }
#pragma unroll
    for (int t = 0; t < 4; t++) {
        int colb = ncol0 + t * 16 + l15;
        float bv = bc[colb];
#pragma unroll
        for (int r = 0; r < 4; r++) {
            float v = acc[t][r] + bv;
            mid[lhi * 4 + r][colb] = (_Float16)(v > 0.f ? v : 0.f);
        }
    }
    __syncthreads();
    // phase 2: each wave computes output cols [wave*16, wave*16+16)
    f32x4 acc2 = (f32x4){0.f, 0.f, 0.f, 0.f};
    int colb = wave * 16 + l15;
    const _Float16* brow = Wf + (size_t)colb * F + lhi * 8;
#pragma unroll
    for (int kt = 0; kt < 8; kt++) {
        f16x8 a = *(const f16x8*)&mid[l15][lhi * 8 + kt * 32];
        f16x8 b = *(const f16x8*)(brow + kt * 32);
        acc2 = __builtin_amdgcn_mfma_f32_16x16x32_f16(a, b, acc2, 0, 0, 0);
    }
    float bv = bf[colb];
#pragma unroll
    for (int r = 0; r < 4; r++) {
        int row = row0 + lhi * 4 + r;
        out[(size_t)row * NCLS + colb] = acc2[r] + bv;
    }
}

extern "C" void kernel_launch(void* const* d_in, const int* in_sizes, int n_in,
                              void* d_out, int out_size, void* d_ws, size_t ws_size,
                              hipStream_t stream) {
    const float* features = (const float*)d_in[0];
    const int* edge_src = (const int*)d_in[1];
    const int* edge_dst = (const int*)d_in[2];
    const float* ln_gamma = (const float*)d_in[3];
    const float* ln_beta = (const float*)d_in[4];
    const float* W_conv = (const float*)d_in[5];
    const float* b_conv = (const float*)d_in[6];
    const float* W_fc = (const float*)d_in[7];
    const float* b_fc = (const float*)d_in[8];
    float* out = (float*)d_out;

    char* w = (char*)d_ws;
    const size_t HB2 = (size_t)NND * F * 2;            // 51,200,000 (fp16 h)
    _Float16* hA = (_Float16*)(w + 0);
    _Float16* hB = (_Float16*)(w + HB2);
    int* col = (int*)(w + 2 * HB2);                    // 102,400,000
    int* deg = (int*)(w + 115200000);
    int* start = (int*)(w + 115600000);
    int* cursor = (int*)(w + 116000000);
    float* norm = (float*)(w + 116400000);
    int* bsum = (int*)(w + 116800000);
    _Float16* Wc16 = (_Float16*)(w + 116802048);
    _Float16* Wf16 = (_Float16*)(w + 116933120);

    hipMemsetAsync(deg, 0, NND * sizeof(int), stream);
    hipMemsetAsync(cursor, 0, NND * sizeof(int), stream);

    const int EB = (NED + 255) / 256;   // 12500
    const int NB = (NND + 255) / 256;   // 391

    k_deg<<<EB, 256, 0, stream>>>(edge_dst, deg);
    k_scan1<<<NB, 256, 0, stream>>>(deg, start, bsum);
    k_scan2<<<1, 512, 0, stream>>>(bsum, NB);
    k_scan3<<<NB, 256, 0, stream>>>(start, bsum, deg, norm);
    k_fill<<<EB, 256, 0, stream>>>(edge_src, edge_dst, start, cursor, col);

    k_ln<<<NND / 4, 256, 0, stream>>>(features, ln_gamma, ln_beta, norm, hA);

    k_hop<0><<<NND / 4, 256, 0, stream>>>(hA, hB, start, deg, col, norm);
    k_hop<0><<<NND / 4, 256, 0, stream>>>(hB, hA, start, deg, col, norm);
    k_hop<1><<<NND / 4, 256, 0, stream>>>(hA, hB, start, deg, col, norm);

    k_cast<<<(F * F / 4 + 255) / 256, 256, 0, stream>>>((const float4*)W_conv, (f16x4*)Wc16, F * F / 4);
    k_cast<<<(NCLS * F / 4 + 255) / 256, 256, 0, stream>>>((const float4*)W_fc, (f16x4*)Wf16, NCLS * F / 4);

    k_gemm<<<NND / 16, 256, 0, stream>>>(hB, Wc16, b_conv, Wf16, b_fc, out);
}